// Round 2
// baseline (1651.300 us; speedup 1.0000x reference)
//
#include <hip/hip_runtime.h>
#include <hip/hip_bf16.h>

#define TT 4096   // B*S tokens
#define HD 1024   // hidden
#define ID 2816   // intermediate
#define ER 7      // routed experts
#define HI (HD * ID)

typedef short s16x8 __attribute__((ext_vector_type(8)));
typedef float f32x4 __attribute__((ext_vector_type(4)));

__device__ __forceinline__ uint32_t pkbf(float a, float b) {
    union { __hip_bfloat16 h[2]; uint32_t u; } z;
    z.h[0] = __float2bfloat16(a);
    z.h[1] = __float2bfloat16(b);
    return z.u;
}

__device__ __forceinline__ void gl_lds16(const void* g, void* l) {
    __builtin_amdgcn_global_load_lds(
        (const __attribute__((address_space(1))) uint32_t*)g,
        (__attribute__((address_space(3))) uint32_t*)l, 16, 0, 0);
}

// ---------------- router: 1 wave per token (fp32 in, fp32 out) ----------------
__global__ __launch_bounds__(64) void router_kernel(
    const float* __restrict__ x, const float* __restrict__ rw,
    const float* __restrict__ rbias, float* __restrict__ combine)
{
    const int t = blockIdx.x;
    const int lane = threadIdx.x;
    const float* xt = x + (size_t)t * HD;
    float acc[ER];
#pragma unroll
    for (int e = 0; e < ER; ++e) acc[e] = 0.f;
    for (int h = lane; h < HD; h += 64) {
        const float xv = xt[h];
#pragma unroll
        for (int e = 0; e < ER; ++e)
            acc[e] += xv * rw[h * ER + e];
    }
#pragma unroll
    for (int e = 0; e < ER; ++e) {
        float v = acc[e];
#pragma unroll
        for (int off = 32; off > 0; off >>= 1) v += __shfl_down(v, off, 64);
        acc[e] = v;
    }
    if (lane == 0) {
        float p[ER];
#pragma unroll
        for (int e = 0; e < ER; ++e) {
            const float lg = acc[e] + rbias[e];
            p[e] = 1.f / (1.f + __expf(-lg));
        }
        int i1 = 0;
#pragma unroll
        for (int e = 1; e < ER; ++e) if (p[e] > p[i1]) i1 = e;
        int i2 = (i1 == 0) ? 1 : 0;
#pragma unroll
        for (int e = 0; e < ER; ++e) {
            if (e == i1 || e == i2) continue;
            if (p[e] > p[i2]) i2 = e;
        }
        const float s = p[i1] + p[i2];
        float w[8];
#pragma unroll
        for (int e = 0; e < 8; ++e) w[e] = 0.f;
        w[i1] = p[i1] / s;
        w[i2] = p[i2] / s;
        w[7] = 1.f;   // shared-expert weight
        float* cb = combine + (size_t)t * 8;
#pragma unroll
        for (int e = 0; e < 8; ++e) cb[e] = w[e];
    }
}

// ---------------- transpose+convert: fp32 [K][N] -> bf16 [N][K], 8 matrices ----
__global__ __launch_bounds__(256) void txp_kernel(
    const float* __restrict__ Wsh, const float* __restrict__ Wrt,
    __hip_bfloat16* __restrict__ dst, int K, int N)
{
    __shared__ float lds[64 * 65];
    const int z = blockIdx.z;
    const float* src = (z < ER) ? (Wrt + (size_t)z * HI) : Wsh;
    __hip_bfloat16* out = dst + (size_t)z * HI;
    const int n0 = blockIdx.x * 64, k0 = blockIdx.y * 64;
    const int t = threadIdx.x;
    const int r = t >> 4, c = (t & 15) * 4;
#pragma unroll
    for (int i = 0; i < 4; ++i) {
        const float4 v = *(const float4*)(src + (size_t)(k0 + r + 16 * i) * N + n0 + c);
        float* p = &lds[(r + 16 * i) * 65 + c];
        p[0] = v.x; p[1] = v.y; p[2] = v.z; p[3] = v.w;
    }
    __syncthreads();
    const int nr = t >> 3, kc = (t & 7) * 8;
#pragma unroll
    for (int i = 0; i < 2; ++i) {
        const int nn = nr + 32 * i;
        uint32_t w[4];
#pragma unroll
        for (int j = 0; j < 4; ++j)
            w[j] = pkbf(lds[(kc + 2 * j) * 65 + nn], lds[(kc + 2 * j + 1) * 65 + nn]);
        *(uint4*)(out + (size_t)(n0 + nn) * K + k0 + kc) = *(uint4*)w;
    }
}

// ---------------- fp32 -> bf16 straight convert (x) ----------------
__global__ __launch_bounds__(256) void cvt_kernel(
    const float* __restrict__ a, __hip_bfloat16* __restrict__ o)
{
    const size_t i = ((size_t)blockIdx.x * 256 + threadIdx.x) * 8;
    const float4 v0 = *(const float4*)(a + i);
    const float4 v1 = *(const float4*)(a + i + 4);
    uint32_t w[4] = { pkbf(v0.x, v0.y), pkbf(v0.z, v0.w),
                      pkbf(v1.x, v1.y), pkbf(v1.z, v1.w) };
    *(uint4*)(o + i) = *(uint4*)w;
}

__global__ __launch_bounds__(256) void zero_kernel(float* __restrict__ o)
{
    const size_t i = ((size_t)blockIdx.x * 256 + threadIdx.x) * 4;
    *(float4*)(o + i) = float4{0.f, 0.f, 0.f, 0.f};
}

// ======================================================================
// gate+up GEMM, expert-group of g = gridDim.z experts per launch.
// BK=64 (16 K-iters: half the barrier drains of BK=32).
// LDS XOR swizzle (rule-21 both-sides): linear gl_lds dest, pre-swizzled
// global source slot  slot^(row&7), XOR'd ds_read -> balanced banks.
// XCD-exclusive decode: xcd = lid&7 owns one expert (or a 11x8..22x32
// sub-tile of one expert's grid) -> minimal per-XCD L2 working set.
// Epilogue folds the per-token combine weight into H (down is linear).
// ======================================================================
__global__ __launch_bounds__(256, 3) void gu_kernel_g(
    const __hip_bfloat16* __restrict__ X,
    const __hip_bfloat16* __restrict__ Wg,   // [8][ID][HD]
    const __hip_bfloat16* __restrict__ Wu,
    const float* __restrict__ combine,       // [TT][8]
    __hip_bfloat16* __restrict__ H,          // [TT][g*ID]
    int e0)
{
    __shared__ __hip_bfloat16 sA[128 * 64];
    __shared__ __hip_bfloat16 sG[128 * 64];
    __shared__ __hip_bfloat16 sU[128 * 64];
    const int tid = threadIdx.x;
    const int g = gridDim.z;

    // XCD-exclusive partition. nwg = 704*g; lid&7 == hardware XCD.
    const int lid = blockIdx.x + 22 * blockIdx.y + 704 * blockIdx.z;
    const int xcd = lid & 7;
    const int w = lid >> 3;            // [0, 88g)
    const int xpe = 8 / g;             // XCDs per expert
    const int el = xcd / xpe;          // group-local expert
    const int t = xcd % xpe;
    const int cx = (xpe >= 2) ? 2 : 1;
    const int tw = 22 / cx;            // 11 or 22
    const int th = 32 / (xpe / cx);    // 8/16/32
    const int bx = (t % cx) * tw + (w % tw);
    const int by = (t / cx) * th + (w / tw);

    const int e = e0 + el;
    const int n0 = bx * 128, m0 = by * 128;
    const __hip_bfloat16* Bg = Wg + (size_t)e * HI;
    const __hip_bfloat16* Bu = Wu + (size_t)e * HI;
    const int ldH = g * ID;

    const int lane = tid & 63, wave = tid >> 6;
    const int wm = (wave >> 1) * 64, wn = (wave & 1) * 64;
    const int r = lane & 15, quad = lane >> 4;

    f32x4 ag[4][4], au[4][4];
#pragma unroll
    for (int i = 0; i < 4; ++i)
#pragma unroll
        for (int j = 0; j < 4; ++j) {
            ag[i][j] = (f32x4){0.f, 0.f, 0.f, 0.f};
            au[i][j] = (f32x4){0.f, 0.f, 0.f, 0.f};
        }

    // staging: thread -> (row = tid>>3 within 32-row chunk, 16B slot = tid&7)
    const int trow = tid >> 3, tslot = tid & 7;
    const int gs8 = ((tslot ^ (trow & 7)) << 3);   // swizzled source slot (elems)
    const size_t aof = (size_t)(m0 + trow) * HD + gs8;
    const size_t bof = (size_t)(n0 + trow) * HD + gs8;
    char* lA = (char*)sA + tid * 16;
    char* lG = (char*)sG + tid * 16;
    char* lU = (char*)sU + tid * 16;

    // read-side XOR per K-half
    const int xs0 = ((quad ^ (r & 7)) << 4);
    const int xs1 = (((4 | quad) ^ (r & 7)) << 4);

    for (int kb = 0; kb < HD; kb += 64) {
#pragma unroll
        for (int c = 0; c < 4; ++c) {
            const size_t cs = (size_t)c * 32 * HD + kb;
            gl_lds16(X  + aof + cs, lA + c * 4096);
            gl_lds16(Bg + bof + cs, lG + c * 4096);
            gl_lds16(Bu + bof + cs, lU + c * 4096);
        }
        __syncthreads();
#pragma unroll
        for (int h = 0; h < 2; ++h) {
            const int xh = h ? xs1 : xs0;
            s16x8 af[4], bg[4], bu[4];
#pragma unroll
            for (int mi = 0; mi < 4; ++mi)
                af[mi] = *(const s16x8*)((const char*)sA + (wm + mi * 16 + r) * 128 + xh);
#pragma unroll
            for (int ni = 0; ni < 4; ++ni) {
                bg[ni] = *(const s16x8*)((const char*)sG + (wn + ni * 16 + r) * 128 + xh);
                bu[ni] = *(const s16x8*)((const char*)sU + (wn + ni * 16 + r) * 128 + xh);
            }
#pragma unroll
            for (int mi = 0; mi < 4; ++mi)
#pragma unroll
                for (int ni = 0; ni < 4; ++ni) {
                    ag[mi][ni] = __builtin_amdgcn_mfma_f32_16x16x32_bf16(af[mi], bg[ni], ag[mi][ni], 0, 0, 0);
                    au[mi][ni] = __builtin_amdgcn_mfma_f32_16x16x32_bf16(af[mi], bu[ni], au[mi][ni], 0, 0, 0);
                }
        }
        __syncthreads();
    }

    const int colb = el * ID;
#pragma unroll
    for (int mi = 0; mi < 4; ++mi)
#pragma unroll
        for (int i = 0; i < 4; ++i) {
            const int grow = m0 + wm + mi * 16 + quad * 4 + i;
            const float wcb = combine[(size_t)grow * 8 + e];
#pragma unroll
            for (int ni = 0; ni < 4; ++ni) {
                const int gcol = n0 + wn + ni * 16 + r;
                const float gv = ag[mi][ni][i];
                const float uv = au[mi][ni][i];
                const float hv = (gv / (1.f + __expf(-gv))) * uv * wcb;
                H[(size_t)grow * ldH + colb + gcol] = __float2bfloat16(hv);
            }
        }
}

// ======================================================================
// down GEMM over the g-expert group (combine already folded into H).
// grid (8,32,2); z-split: g==1 -> ID halves; g>=2 -> expert halves.
// Same BK=64 + XOR swizzle + XCD-exclusive chunking (4bx x 16by / XCD).
// atomicAdd into pre-zeroed fp32 Out.
// ======================================================================
__global__ __launch_bounds__(256, 3) void down_kernel_g(
    const __hip_bfloat16* __restrict__ Hb,   // [TT][g*ID] group buffer
    const __hip_bfloat16* __restrict__ Wd,   // group base: [g][HD][ID]
    float* __restrict__ Out, int g)
{
    __shared__ __hip_bfloat16 sA[128 * 64];
    __shared__ __hip_bfloat16 sB[128 * 64];
    const int tid = threadIdx.x;

    const int lid = blockIdx.x + 8 * blockIdx.y + 256 * blockIdx.z;
    const int xcd = lid & 7;
    const int w = lid >> 3;                  // [0,64)
    const int sz = xcd >> 2;                 // split half
    const int q = xcd & 3;
    const int bx = (q & 1) * 4 + (w & 3);
    const int by = (q >> 1) * 16 + (w >> 2);

    const int n0 = bx * 128, m0 = by * 128;
    const int ldH = g * ID;
    int e_b, e_e, k0, k1;
    if (g == 1) { e_b = 0; e_e = 1; k0 = sz * (ID / 2); k1 = k0 + ID / 2; }
    else        { e_b = sz * (g >> 1); e_e = e_b + (g >> 1); k0 = 0; k1 = ID; }

    const int lane = tid & 63, wave = tid >> 6;
    const int wm = (wave >> 1) * 64, wn = (wave & 1) * 64;
    const int r = lane & 15, quad = lane >> 4;

    f32x4 acc[4][4];
#pragma unroll
    for (int i = 0; i < 4; ++i)
#pragma unroll
        for (int j = 0; j < 4; ++j)
            acc[i][j] = (f32x4){0.f, 0.f, 0.f, 0.f};

    const int trow = tid >> 3, tslot = tid & 7;
    const int gs8 = ((tslot ^ (trow & 7)) << 3);
    char* lA = (char*)sA + tid * 16;
    char* lB = (char*)sB + tid * 16;
    const int xs0 = ((quad ^ (r & 7)) << 4);
    const int xs1 = (((4 | quad) ^ (r & 7)) << 4);

    for (int e = e_b; e < e_e; ++e) {
        const size_t abase = (size_t)(m0 + trow) * ldH + (size_t)e * ID + gs8;
        const size_t bbase = (size_t)e * HI + (size_t)(n0 + trow) * ID + gs8;
        for (int kb = k0; kb < k1; kb += 64) {
#pragma unroll
            for (int c = 0; c < 4; ++c) {
                gl_lds16(Hb + abase + (size_t)c * 32 * ldH + kb, lA + c * 4096);
                gl_lds16(Wd + bbase + (size_t)c * 32 * ID  + kb, lB + c * 4096);
            }
            __syncthreads();
#pragma unroll
            for (int h = 0; h < 2; ++h) {
                const int xh = h ? xs1 : xs0;
                s16x8 af[4], bf[4];
#pragma unroll
                for (int mi = 0; mi < 4; ++mi)
                    af[mi] = *(const s16x8*)((const char*)sA + (wm + mi * 16 + r) * 128 + xh);
#pragma unroll
                for (int ni = 0; ni < 4; ++ni)
                    bf[ni] = *(const s16x8*)((const char*)sB + (wn + ni * 16 + r) * 128 + xh);
#pragma unroll
                for (int mi = 0; mi < 4; ++mi)
#pragma unroll
                    for (int ni = 0; ni < 4; ++ni)
                        acc[mi][ni] = __builtin_amdgcn_mfma_f32_16x16x32_bf16(af[mi], bf[ni], acc[mi][ni], 0, 0, 0);
            }
            __syncthreads();
        }
    }

#pragma unroll
    for (int mi = 0; mi < 4; ++mi)
#pragma unroll
        for (int i = 0; i < 4; ++i) {
            const int grow = m0 + wm + mi * 16 + quad * 4 + i;
#pragma unroll
            for (int ni = 0; ni < 4; ++ni) {
                const int gcol = n0 + wn + ni * 16 + r;
                atomicAdd(&Out[(size_t)grow * HD + gcol], acc[mi][ni][i]);
            }
        }
}

// ================= fallback path (round-3, validated) =================
template <int MODE, int AF32>
__global__ __launch_bounds__(256) void gemm_kernel(
    const void* __restrict__ Av, const float* __restrict__ B,
    __hip_bfloat16* __restrict__ Hbuf, float* __restrict__ Out,
    const float* __restrict__ combine, int M, int N, int K, int wcol, int beta)
{
    __shared__ uint32_t ldsA[128 * 20];
    __shared__ uint32_t ldsB[128 * 20];
    const int tid = threadIdx.x;
    const int n0 = blockIdx.x * 128;
    const int m0 = blockIdx.y * 128;
    const int lane = tid & 63, wave = tid >> 6;
    const int wm = (wave >> 1) * 64, wn = (wave & 1) * 64;
    const int r = lane & 15, quad = lane >> 4;
    f32x4 acc[4][4];
#pragma unroll
    for (int i = 0; i < 4; ++i)
#pragma unroll
        for (int j = 0; j < 4; ++j) acc[i][j] = (f32x4){0.f, 0.f, 0.f, 0.f};
    for (int kb = 0; kb < K; kb += 32) {
        if (AF32) {
            const float* A = (const float*)Av;
            const int arow = tid >> 1, ah = tid & 1;
            const float* ap = A + (size_t)(m0 + arow) * K + kb + ah * 16;
            const float4 f0 = *(const float4*)ap;
            const float4 f1 = *(const float4*)(ap + 4);
            const float4 f2 = *(const float4*)(ap + 8);
            const float4 f3 = *(const float4*)(ap + 12);
            uint4 w0, w1;
            w0.x = pkbf(f0.x, f0.y); w0.y = pkbf(f0.z, f0.w);
            w0.z = pkbf(f1.x, f1.y); w0.w = pkbf(f1.z, f1.w);
            w1.x = pkbf(f2.x, f2.y); w1.y = pkbf(f2.z, f2.w);
            w1.z = pkbf(f3.x, f3.y); w1.w = pkbf(f3.z, f3.w);
            *(uint4*)&ldsA[arow * 20 + ah * 8] = w0;
            *(uint4*)&ldsA[arow * 20 + ah * 8 + 4] = w1;
        } else {
            const __hip_bfloat16* A = (const __hip_bfloat16*)Av;
            const int arow = tid >> 2, akc = tid & 3;
            const uint4 v0 = *(const uint4*)(A + (size_t)(m0 + arow) * K + kb + akc * 8);
            const uint4 v1 = *(const uint4*)(A + (size_t)(m0 + arow + 64) * K + kb + akc * 8);
            *(uint4*)&ldsA[arow * 20 + akc * 4] = v0;
            *(uint4*)&ldsA[(arow + 64) * 20 + akc * 4] = v1;
        }
        {
            const int bkp = tid >> 4, bnc = tid & 15;
            const float* bp0 = B + (size_t)(kb + 2 * bkp) * N + n0 + bnc * 8;
            const float* bp1 = bp0 + N;
            const float4 a0 = *(const float4*)bp0;
            const float4 a1 = *(const float4*)(bp0 + 4);
            const float4 b0 = *(const float4*)bp1;
            const float4 b1 = *(const float4*)(bp1 + 4);
            const float r0[8] = {a0.x, a0.y, a0.z, a0.w, a1.x, a1.y, a1.z, a1.w};
            const float r1[8] = {b0.x, b0.y, b0.z, b0.w, b1.x, b1.y, b1.z, b1.w};
            const int grp = (((bkp >> 2) ^ (bnc & 3)) << 2);
            const int kk = bkp & 3;
#pragma unroll
            for (int j = 0; j < 8; ++j)
                ldsB[(bnc * 8 + j) * 20 + grp + kk] = pkbf(r0[j], r1[j]);
        }
        __syncthreads();
        s16x8 af[4], bfr[4];
#pragma unroll
        for (int mi = 0; mi < 4; ++mi)
            af[mi] = *(const s16x8*)&ldsA[(wm + mi * 16 + r) * 20 + quad * 4];
#pragma unroll
        for (int ni = 0; ni < 4; ++ni) {
            const int nl = wn + ni * 16 + r;
            bfr[ni] = *(const s16x8*)&ldsB[nl * 20 + ((quad ^ ((nl >> 3) & 3)) << 2)];
        }
#pragma unroll
        for (int mi = 0; mi < 4; ++mi)
#pragma unroll
            for (int ni = 0; ni < 4; ++ni)
                acc[mi][ni] = __builtin_amdgcn_mfma_f32_16x16x32_bf16(af[mi], bfr[ni], acc[mi][ni], 0, 0, 0);
        __syncthreads();
    }
#pragma unroll
    for (int mi = 0; mi < 4; ++mi)
#pragma unroll
        for (int i = 0; i < 4; ++i) {
            const int grow = m0 + wm + mi * 16 + quad * 4 + i;
#pragma unroll
            for (int ni = 0; ni < 4; ++ni) {
                const int gcol = n0 + wn + ni * 16 + r;
                const float v = acc[mi][ni][i];
                if (MODE == 0) {
                    Hbuf[(size_t)grow * N + gcol] = __float2bfloat16(v / (1.f + __expf(-v)));
                } else if (MODE == 1) {
                    const size_t idx = (size_t)grow * N + gcol;
                    Hbuf[idx] = __float2bfloat16(__bfloat162float(Hbuf[idx]) * v);
                } else {
                    const size_t idx = (size_t)grow * N + gcol;
                    const float w = combine[(size_t)grow * 8 + wcol];
                    Out[idx] = (beta ? Out[idx] : 0.f) + w * v;
                }
            }
        }
}

extern "C" void kernel_launch(void* const* d_in, const int* in_sizes, int n_in,
                              void* d_out, int out_size, void* d_ws, size_t ws_size,
                              hipStream_t stream)
{
    (void)in_sizes; (void)n_in; (void)out_size;
    const float* x  = (const float*)d_in[0];
    const float* rw = (const float*)d_in[1];
    const float* rb = (const float*)d_in[2];
    const float* sg = (const float*)d_in[3];
    const float* su = (const float*)d_in[4];
    const float* sd = (const float*)d_in[5];
    const float* rg = (const float*)d_in[6];
    const float* ru = (const float*)d_in[7];
    const float* rd = (const float*)d_in[8];
    float* out = (float*)d_out;

    const size_t SZ_COMBINE = (size_t)TT * 8 * 4;
    const size_t SZ_XB      = (size_t)TT * HD * 2;
    const size_t SZ_W       = (size_t)8 * HI * 2;

    // largest expert-group g whose hbuf fits the workspace
    int g = 0;
    for (int c = 8; c >= 1; c >>= 1) {
        const size_t need = SZ_COMBINE + SZ_XB + (size_t)TT * c * ID * 2 + 3 * SZ_W;
        if (ws_size >= need) { g = c; break; }
    }

    if (g) {
        char* p = (char*)d_ws;
        float* combine = (float*)p;            p += SZ_COMBINE;
        __hip_bfloat16* xb   = (__hip_bfloat16*)p; p += SZ_XB;
        __hip_bfloat16* hbuf = (__hip_bfloat16*)p; p += (size_t)TT * g * ID * 2;
        __hip_bfloat16* wtg  = (__hip_bfloat16*)p; p += SZ_W;
        __hip_bfloat16* wtu  = (__hip_bfloat16*)p; p += SZ_W;
        __hip_bfloat16* wtd  = (__hip_bfloat16*)p;

        zero_kernel<<<(TT * HD) / 1024, 256, 0, stream>>>(out);
        cvt_kernel<<<(TT * HD) / 2048, 256, 0, stream>>>(x, xb);
        txp_kernel<<<dim3(ID / 64, HD / 64, 8), 256, 0, stream>>>(sg, rg, wtg, HD, ID);
        txp_kernel<<<dim3(ID / 64, HD / 64, 8), 256, 0, stream>>>(su, ru, wtu, HD, ID);
        txp_kernel<<<dim3(HD / 64, ID / 64, 8), 256, 0, stream>>>(sd, rd, wtd, ID, HD);
        router_kernel<<<TT, 64, 0, stream>>>(x, rw, rb, combine);

        for (int gi = 0; gi < 8 / g; ++gi) {
            gu_kernel_g<<<dim3(22, 32, g), 256, 0, stream>>>(
                xb, wtg, wtu, combine, hbuf, gi * g);
            down_kernel_g<<<dim3(8, 32, 2), 256, 0, stream>>>(
                hbuf, wtd + (size_t)gi * g * HI, out, g);
        }
    } else {
        // fallback: round-3 validated path (~23.2 MB ws)
        float* combine = (float*)d_ws;
        __hip_bfloat16* hbuf = (__hip_bfloat16*)(combine + (size_t)TT * 8);
        router_kernel<<<TT, 64, 0, stream>>>(x, rw, rb, combine);
        dim3 blk(256);
        dim3 gH(ID / 128, TT / 128);
        dim3 gD(HD / 128, TT / 128);
        for (int p = 0; p < 8; ++p) {
            const float *wg, *wu, *wd;
            if (p < ER) {
                wg = rg + (size_t)p * HI;
                wu = ru + (size_t)p * HI;
                wd = rd + (size_t)p * HI;
            } else {
                wg = sg; wu = su; wd = sd;
            }
            gemm_kernel<0, 1><<<gH, blk, 0, stream>>>(x, wg, hbuf, nullptr, nullptr, TT, ID, HD, 0, 0);
            gemm_kernel<1, 1><<<gH, blk, 0, stream>>>(x, wu, hbuf, nullptr, nullptr, TT, ID, HD, 0, 0);
            gemm_kernel<2, 0><<<gD, blk, 0, stream>>>(hbuf, wd, nullptr, out, combine, TT, HD, ID, p, p == 0 ? 0 : 1);
        }
    }
}

// Round 3
// 1358.112 us; speedup vs baseline: 1.2159x; 1.2159x over previous
//
#include <hip/hip_runtime.h>
#include <hip/hip_bf16.h>

#define TT 4096   // B*S tokens
#define HD 1024   // hidden
#define ID 2816   // intermediate
#define ER 7      // routed experts
#define HI (HD * ID)

typedef short s16x8 __attribute__((ext_vector_type(8)));
typedef float f32x4 __attribute__((ext_vector_type(4)));

__device__ __forceinline__ uint32_t pkbf(float a, float b) {
    union { __hip_bfloat16 h[2]; uint32_t u; } z;
    z.h[0] = __float2bfloat16(a);
    z.h[1] = __float2bfloat16(b);
    return z.u;
}

__device__ __forceinline__ void gl_lds16(const void* g, void* l) {
    __builtin_amdgcn_global_load_lds(
        (const __attribute__((address_space(1))) uint32_t*)g,
        (__attribute__((address_space(3))) uint32_t*)l, 16, 0, 0);
}

// ---------------- router: 1 wave per token (fp32 in, fp32 out) ----------------
__global__ __launch_bounds__(64) void router_kernel(
    const float* __restrict__ x, const float* __restrict__ rw,
    const float* __restrict__ rbias, float* __restrict__ combine)
{
    const int t = blockIdx.x;
    const int lane = threadIdx.x;
    const float* xt = x + (size_t)t * HD;
    float acc[ER];
#pragma unroll
    for (int e = 0; e < ER; ++e) acc[e] = 0.f;
    for (int h = lane; h < HD; h += 64) {
        const float xv = xt[h];
#pragma unroll
        for (int e = 0; e < ER; ++e)
            acc[e] += xv * rw[h * ER + e];
    }
#pragma unroll
    for (int e = 0; e < ER; ++e) {
        float v = acc[e];
#pragma unroll
        for (int off = 32; off > 0; off >>= 1) v += __shfl_down(v, off, 64);
        acc[e] = v;
    }
    if (lane == 0) {
        float p[ER];
#pragma unroll
        for (int e = 0; e < ER; ++e) {
            const float lg = acc[e] + rbias[e];
            p[e] = 1.f / (1.f + __expf(-lg));
        }
        int i1 = 0;
#pragma unroll
        for (int e = 1; e < ER; ++e) if (p[e] > p[i1]) i1 = e;
        int i2 = (i1 == 0) ? 1 : 0;
#pragma unroll
        for (int e = 0; e < ER; ++e) {
            if (e == i1 || e == i2) continue;
            if (p[e] > p[i2]) i2 = e;
        }
        const float s = p[i1] + p[i2];
        float w[8];
#pragma unroll
        for (int e = 0; e < 8; ++e) w[e] = 0.f;
        w[i1] = p[i1] / s;
        w[i2] = p[i2] / s;
        w[7] = 1.f;   // shared-expert weight
        float* cb = combine + (size_t)t * 8;
#pragma unroll
        for (int e = 0; e < 8; ++e) cb[e] = w[e];
    }
}

// ---------------- transpose+convert: fp32 [K][N] -> bf16 [N][K], 8 matrices ----
__global__ __launch_bounds__(256) void txp_kernel(
    const float* __restrict__ Wsh, const float* __restrict__ Wrt,
    __hip_bfloat16* __restrict__ dst, int K, int N)
{
    __shared__ float lds[64 * 65];
    const int z = blockIdx.z;
    const float* src = (z < ER) ? (Wrt + (size_t)z * HI) : Wsh;
    __hip_bfloat16* out = dst + (size_t)z * HI;
    const int n0 = blockIdx.x * 64, k0 = blockIdx.y * 64;
    const int t = threadIdx.x;
    const int r = t >> 4, c = (t & 15) * 4;
#pragma unroll
    for (int i = 0; i < 4; ++i) {
        const float4 v = *(const float4*)(src + (size_t)(k0 + r + 16 * i) * N + n0 + c);
        float* p = &lds[(r + 16 * i) * 65 + c];
        p[0] = v.x; p[1] = v.y; p[2] = v.z; p[3] = v.w;
    }
    __syncthreads();
    const int nr = t >> 3, kc = (t & 7) * 8;
#pragma unroll
    for (int i = 0; i < 2; ++i) {
        const int nn = nr + 32 * i;
        uint32_t w[4];
#pragma unroll
        for (int j = 0; j < 4; ++j)
            w[j] = pkbf(lds[(kc + 2 * j) * 65 + nn], lds[(kc + 2 * j + 1) * 65 + nn]);
        *(uint4*)(out + (size_t)(n0 + nn) * K + k0 + kc) = *(uint4*)w;
    }
}

// ---------------- fp32 -> bf16 straight convert (x) ----------------
__global__ __launch_bounds__(256) void cvt_kernel(
    const float* __restrict__ a, __hip_bfloat16* __restrict__ o)
{
    const size_t i = ((size_t)blockIdx.x * 256 + threadIdx.x) * 8;
    const float4 v0 = *(const float4*)(a + i);
    const float4 v1 = *(const float4*)(a + i + 4);
    uint32_t w[4] = { pkbf(v0.x, v0.y), pkbf(v0.z, v0.w),
                      pkbf(v1.x, v1.y), pkbf(v1.z, v1.w) };
    *(uint4*)(o + i) = *(uint4*)w;
}

__global__ __launch_bounds__(256) void zero_kernel(float* __restrict__ o)
{
    const size_t i = ((size_t)blockIdx.x * 256 + threadIdx.x) * 4;
    *(float4*)(o + i) = float4{0.f, 0.f, 0.f, 0.f};
}

// ======================================================================
// gate+up GEMM, expert-group of g = gridDim.z experts in ONE launch.
// Round-0 proven BK=32 core (160 VGPR, no occupancy pin -> no spills).
// + XOR swizzle f(row)=(row>>1)&3 (rule-21 both-sides; conflicts->0 in r2)
// + XCD-exclusive 2D chunking (per-XCD L2 working set minimized)
// + combine weight folded into epilogue (down is linear).
// ======================================================================
__global__ __launch_bounds__(256) void gu_kernel_g(
    const __hip_bfloat16* __restrict__ X,
    const __hip_bfloat16* __restrict__ Wg,   // [8][ID][HD]
    const __hip_bfloat16* __restrict__ Wu,
    const float* __restrict__ combine,       // [TT][8]
    __hip_bfloat16* __restrict__ H,          // [TT][g*ID]
    int e0)
{
    __shared__ __hip_bfloat16 sA[128 * 32];
    __shared__ __hip_bfloat16 sG[128 * 32];
    __shared__ __hip_bfloat16 sU[128 * 32];
    const int tid = threadIdx.x;
    const int g = gridDim.z;

    // XCD-exclusive partition. nwg = 704*g; lid&7 == hardware XCD (heuristic).
    const int lid = blockIdx.x + 22 * blockIdx.y + 704 * blockIdx.z;
    const int xcd = lid & 7;
    const int w = lid >> 3;            // [0, 88g)
    const int xpe = 8 / g;             // XCDs per expert
    const int el = xcd / xpe;          // group-local expert
    const int t = xcd % xpe;
    const int cx = (xpe >= 2) ? 2 : 1;
    const int tw = 22 / cx;            // 11 or 22
    const int th = 32 / (xpe / cx);    // 8/16/32
    const int bx = (t % cx) * tw + (w % tw);
    const int by = (t / cx) * th + (w / tw);

    const int e = e0 + el;
    const int n0 = bx * 128, m0 = by * 128;
    const __hip_bfloat16* Bg = Wg + (size_t)e * HI;
    const __hip_bfloat16* Bu = Wu + (size_t)e * HI;
    const int ldH = g * ID;

    const int lane = tid & 63, wave = tid >> 6;
    const int wm = (wave >> 1) * 64, wn = (wave & 1) * 64;
    const int r = lane & 15, quad = lane >> 4;

    f32x4 ag[4][4], au[4][4];
#pragma unroll
    for (int i = 0; i < 4; ++i)
#pragma unroll
        for (int j = 0; j < 4; ++j) {
            ag[i][j] = (f32x4){0.f, 0.f, 0.f, 0.f};
            au[i][j] = (f32x4){0.f, 0.f, 0.f, 0.f};
        }

    // staging: row = tid>>2 (64 rows/chunk), 16B granule = tid&3,
    // swizzled global source slot = (tid&3) ^ ((row>>1)&3); LDS dest linear.
    const int srow = tid >> 2;
    const int sk = ((tid & 3) ^ ((srow >> 1) & 3)) * 8;
    const size_t aoff = (size_t)(m0 + srow) * HD + sk;
    const size_t boff = (size_t)(n0 + srow) * HD + sk;
    char* lA = (char*)sA + tid * 16;
    char* lG = (char*)sG + tid * 16;
    char* lU = (char*)sU + tid * 16;

    // read-side XOR: granule quad lives at quad ^ ((r>>1)&3)
    const int xh = ((quad ^ ((r >> 1) & 3)) << 4);

    for (int kb = 0; kb < HD; kb += 32) {
        gl_lds16(X + aoff + kb, lA);
        gl_lds16(X + aoff + (size_t)64 * HD + kb, lA + 4096);
        gl_lds16(Bg + boff + kb, lG);
        gl_lds16(Bg + boff + (size_t)64 * HD + kb, lG + 4096);
        gl_lds16(Bu + boff + kb, lU);
        gl_lds16(Bu + boff + (size_t)64 * HD + kb, lU + 4096);
        __syncthreads();

        s16x8 af[4], bg[4], bu[4];
#pragma unroll
        for (int mi = 0; mi < 4; ++mi)
            af[mi] = *(const s16x8*)((const char*)sA + (wm + mi * 16 + r) * 64 + xh);
#pragma unroll
        for (int ni = 0; ni < 4; ++ni) {
            bg[ni] = *(const s16x8*)((const char*)sG + (wn + ni * 16 + r) * 64 + xh);
            bu[ni] = *(const s16x8*)((const char*)sU + (wn + ni * 16 + r) * 64 + xh);
        }
#pragma unroll
        for (int mi = 0; mi < 4; ++mi)
#pragma unroll
            for (int ni = 0; ni < 4; ++ni) {
                ag[mi][ni] = __builtin_amdgcn_mfma_f32_16x16x32_bf16(af[mi], bg[ni], ag[mi][ni], 0, 0, 0);
                au[mi][ni] = __builtin_amdgcn_mfma_f32_16x16x32_bf16(af[mi], bu[ni], au[mi][ni], 0, 0, 0);
            }
        __syncthreads();
    }

    const int colb = el * ID;
#pragma unroll
    for (int mi = 0; mi < 4; ++mi)
#pragma unroll
        for (int i = 0; i < 4; ++i) {
            const int grow = m0 + wm + mi * 16 + quad * 4 + i;
            const float wcb = combine[(size_t)grow * 8 + e];
#pragma unroll
            for (int ni = 0; ni < 4; ++ni) {
                const int gcol = n0 + wn + ni * 16 + r;
                const float gv = ag[mi][ni][i];
                const float uv = au[mi][ni][i];
                const float hv = (gv / (1.f + __expf(-gv))) * uv * wcb;
                H[(size_t)grow * ldH + colb + gcol] = __float2bfloat16(hv);
            }
        }
}

// ======================================================================
// down GEMM over the g-expert group (combine already folded into H).
// Round-0 BK=32 core, same swizzle, XCD-exclusive chunks, grid (8,32,2);
// z-split: g==1 -> ID halves; g>=2 -> expert halves. atomicAdd epilogue.
// ======================================================================
__global__ __launch_bounds__(256) void down_kernel_g(
    const __hip_bfloat16* __restrict__ Hb,   // [TT][g*ID]
    const __hip_bfloat16* __restrict__ Wd,   // group base: [g][HD][ID]
    float* __restrict__ Out, int g)
{
    __shared__ __hip_bfloat16 sA[128 * 32];
    __shared__ __hip_bfloat16 sB[128 * 32];
    const int tid = threadIdx.x;

    const int lid = blockIdx.x + 8 * blockIdx.y + 256 * blockIdx.z;
    const int xcd = lid & 7;
    const int w = lid >> 3;                  // [0,64)
    const int sz = xcd >> 2;                 // split half
    const int q = xcd & 3;
    const int bx = (q & 1) * 4 + (w & 3);
    const int by = (q >> 1) * 16 + (w >> 2);

    const int n0 = bx * 128, m0 = by * 128;
    const int ldH = g * ID;
    int e_b, e_e, k0, k1;
    if (g == 1) { e_b = 0; e_e = 1; k0 = sz * (ID / 2); k1 = k0 + ID / 2; }
    else        { e_b = sz * (g >> 1); e_e = e_b + (g >> 1); k0 = 0; k1 = ID; }

    const int lane = tid & 63, wave = tid >> 6;
    const int wm = (wave >> 1) * 64, wn = (wave & 1) * 64;
    const int r = lane & 15, quad = lane >> 4;

    f32x4 acc[4][4];
#pragma unroll
    for (int i = 0; i < 4; ++i)
#pragma unroll
        for (int j = 0; j < 4; ++j)
            acc[i][j] = (f32x4){0.f, 0.f, 0.f, 0.f};

    const int srow = tid >> 2;
    const int sk = ((tid & 3) ^ ((srow >> 1) & 3)) * 8;
    char* lA = (char*)sA + tid * 16;
    char* lB = (char*)sB + tid * 16;
    const int xh = ((quad ^ ((r >> 1) & 3)) << 4);

    for (int e = e_b; e < e_e; ++e) {
        const size_t abase = (size_t)(m0 + srow) * ldH + (size_t)e * ID + sk;
        const size_t bbase = (size_t)e * HI + (size_t)(n0 + srow) * ID + sk;
        for (int kb = k0; kb < k1; kb += 32) {
            gl_lds16(Hb + abase + kb, lA);
            gl_lds16(Hb + abase + (size_t)64 * ldH + kb, lA + 4096);
            gl_lds16(Wd + bbase + kb, lB);
            gl_lds16(Wd + bbase + (size_t)64 * ID + kb, lB + 4096);
            __syncthreads();

            s16x8 af[4], bf[4];
#pragma unroll
            for (int mi = 0; mi < 4; ++mi)
                af[mi] = *(const s16x8*)((const char*)sA + (wm + mi * 16 + r) * 64 + xh);
#pragma unroll
            for (int ni = 0; ni < 4; ++ni)
                bf[ni] = *(const s16x8*)((const char*)sB + (wn + ni * 16 + r) * 64 + xh);
#pragma unroll
            for (int mi = 0; mi < 4; ++mi)
#pragma unroll
                for (int ni = 0; ni < 4; ++ni)
                    acc[mi][ni] = __builtin_amdgcn_mfma_f32_16x16x32_bf16(af[mi], bf[ni], acc[mi][ni], 0, 0, 0);
            __syncthreads();
        }
    }

#pragma unroll
    for (int mi = 0; mi < 4; ++mi)
#pragma unroll
        for (int i = 0; i < 4; ++i) {
            const int grow = m0 + wm + mi * 16 + quad * 4 + i;
#pragma unroll
            for (int ni = 0; ni < 4; ++ni) {
                const int gcol = n0 + wn + ni * 16 + r;
                atomicAdd(&Out[(size_t)grow * HD + gcol], acc[mi][ni][i]);
            }
        }
}

// ================= fallback path (round-3, validated) =================
template <int MODE, int AF32>
__global__ __launch_bounds__(256) void gemm_kernel(
    const void* __restrict__ Av, const float* __restrict__ B,
    __hip_bfloat16* __restrict__ Hbuf, float* __restrict__ Out,
    const float* __restrict__ combine, int M, int N, int K, int wcol, int beta)
{
    __shared__ uint32_t ldsA[128 * 20];
    __shared__ uint32_t ldsB[128 * 20];
    const int tid = threadIdx.x;
    const int n0 = blockIdx.x * 128;
    const int m0 = blockIdx.y * 128;
    const int lane = tid & 63, wave = tid >> 6;
    const int wm = (wave >> 1) * 64, wn = (wave & 1) * 64;
    const int r = lane & 15, quad = lane >> 4;
    f32x4 acc[4][4];
#pragma unroll
    for (int i = 0; i < 4; ++i)
#pragma unroll
        for (int j = 0; j < 4; ++j) acc[i][j] = (f32x4){0.f, 0.f, 0.f, 0.f};
    for (int kb = 0; kb < K; kb += 32) {
        if (AF32) {
            const float* A = (const float*)Av;
            const int arow = tid >> 1, ah = tid & 1;
            const float* ap = A + (size_t)(m0 + arow) * K + kb + ah * 16;
            const float4 f0 = *(const float4*)ap;
            const float4 f1 = *(const float4*)(ap + 4);
            const float4 f2 = *(const float4*)(ap + 8);
            const float4 f3 = *(const float4*)(ap + 12);
            uint4 w0, w1;
            w0.x = pkbf(f0.x, f0.y); w0.y = pkbf(f0.z, f0.w);
            w0.z = pkbf(f1.x, f1.y); w0.w = pkbf(f1.z, f1.w);
            w1.x = pkbf(f2.x, f2.y); w1.y = pkbf(f2.z, f2.w);
            w1.z = pkbf(f3.x, f3.y); w1.w = pkbf(f3.z, f3.w);
            *(uint4*)&ldsA[arow * 20 + ah * 8] = w0;
            *(uint4*)&ldsA[arow * 20 + ah * 8 + 4] = w1;
        } else {
            const __hip_bfloat16* A = (const __hip_bfloat16*)Av;
            const int arow = tid >> 2, akc = tid & 3;
            const uint4 v0 = *(const uint4*)(A + (size_t)(m0 + arow) * K + kb + akc * 8);
            const uint4 v1 = *(const uint4*)(A + (size_t)(m0 + arow + 64) * K + kb + akc * 8);
            *(uint4*)&ldsA[arow * 20 + akc * 4] = v0;
            *(uint4*)&ldsA[(arow + 64) * 20 + akc * 4] = v1;
        }
        {
            const int bkp = tid >> 4, bnc = tid & 15;
            const float* bp0 = B + (size_t)(kb + 2 * bkp) * N + n0 + bnc * 8;
            const float* bp1 = bp0 + N;
            const float4 a0 = *(const float4*)bp0;
            const float4 a1 = *(const float4*)(bp0 + 4);
            const float4 b0 = *(const float4*)bp1;
            const float4 b1 = *(const float4*)(bp1 + 4);
            const float r0[8] = {a0.x, a0.y, a0.z, a0.w, a1.x, a1.y, a1.z, a1.w};
            const float r1[8] = {b0.x, b0.y, b0.z, b0.w, b1.x, b1.y, b1.z, b1.w};
            const int grp = (((bkp >> 2) ^ (bnc & 3)) << 2);
            const int kk = bkp & 3;
#pragma unroll
            for (int j = 0; j < 8; ++j)
                ldsB[(bnc * 8 + j) * 20 + grp + kk] = pkbf(r0[j], r1[j]);
        }
        __syncthreads();
        s16x8 af[4], bfr[4];
#pragma unroll
        for (int mi = 0; mi < 4; ++mi)
            af[mi] = *(const s16x8*)&ldsA[(wm + mi * 16 + r) * 20 + quad * 4];
#pragma unroll
        for (int ni = 0; ni < 4; ++ni) {
            const int nl = wn + ni * 16 + r;
            bfr[ni] = *(const s16x8*)&ldsB[nl * 20 + ((quad ^ ((nl >> 3) & 3)) << 2)];
        }
#pragma unroll
        for (int mi = 0; mi < 4; ++mi)
#pragma unroll
            for (int ni = 0; ni < 4; ++ni)
                acc[mi][ni] = __builtin_amdgcn_mfma_f32_16x16x32_bf16(af[mi], bfr[ni], acc[mi][ni], 0, 0, 0);
        __syncthreads();
    }
#pragma unroll
    for (int mi = 0; mi < 4; ++mi)
#pragma unroll
        for (int i = 0; i < 4; ++i) {
            const int grow = m0 + wm + mi * 16 + quad * 4 + i;
#pragma unroll
            for (int ni = 0; ni < 4; ++ni) {
                const int gcol = n0 + wn + ni * 16 + r;
                const float v = acc[mi][ni][i];
                if (MODE == 0) {
                    Hbuf[(size_t)grow * N + gcol] = __float2bfloat16(v / (1.f + __expf(-v)));
                } else if (MODE == 1) {
                    const size_t idx = (size_t)grow * N + gcol;
                    Hbuf[idx] = __float2bfloat16(__bfloat162float(Hbuf[idx]) * v);
                } else {
                    const size_t idx = (size_t)grow * N + gcol;
                    const float w = combine[(size_t)grow * 8 + wcol];
                    Out[idx] = (beta ? Out[idx] : 0.f) + w * v;
                }
            }
        }
}

extern "C" void kernel_launch(void* const* d_in, const int* in_sizes, int n_in,
                              void* d_out, int out_size, void* d_ws, size_t ws_size,
                              hipStream_t stream)
{
    (void)in_sizes; (void)n_in; (void)out_size;
    const float* x  = (const float*)d_in[0];
    const float* rw = (const float*)d_in[1];
    const float* rb = (const float*)d_in[2];
    const float* sg = (const float*)d_in[3];
    const float* su = (const float*)d_in[4];
    const float* sd = (const float*)d_in[5];
    const float* rg = (const float*)d_in[6];
    const float* ru = (const float*)d_in[7];
    const float* rd = (const float*)d_in[8];
    float* out = (float*)d_out;

    const size_t SZ_COMBINE = (size_t)TT * 8 * 4;
    const size_t SZ_XB      = (size_t)TT * HD * 2;
    const size_t SZ_W       = (size_t)8 * HI * 2;

    // largest expert-group g whose hbuf fits the workspace
    int g = 0;
    for (int c = 8; c >= 1; c >>= 1) {
        const size_t need = SZ_COMBINE + SZ_XB + (size_t)TT * c * ID * 2 + 3 * SZ_W;
        if (ws_size >= need) { g = c; break; }
    }

    if (g) {
        char* p = (char*)d_ws;
        float* combine = (float*)p;            p += SZ_COMBINE;
        __hip_bfloat16* xb   = (__hip_bfloat16*)p; p += SZ_XB;
        __hip_bfloat16* hbuf = (__hip_bfloat16*)p; p += (size_t)TT * g * ID * 2;
        __hip_bfloat16* wtg  = (__hip_bfloat16*)p; p += SZ_W;
        __hip_bfloat16* wtu  = (__hip_bfloat16*)p; p += SZ_W;
        __hip_bfloat16* wtd  = (__hip_bfloat16*)p;

        zero_kernel<<<(TT * HD) / 1024, 256, 0, stream>>>(out);
        cvt_kernel<<<(TT * HD) / 2048, 256, 0, stream>>>(x, xb);
        txp_kernel<<<dim3(ID / 64, HD / 64, 8), 256, 0, stream>>>(sg, rg, wtg, HD, ID);
        txp_kernel<<<dim3(ID / 64, HD / 64, 8), 256, 0, stream>>>(su, ru, wtu, HD, ID);
        txp_kernel<<<dim3(HD / 64, ID / 64, 8), 256, 0, stream>>>(sd, rd, wtd, ID, HD);
        router_kernel<<<TT, 64, 0, stream>>>(x, rw, rb, combine);

        for (int gi = 0; gi < 8 / g; ++gi) {
            gu_kernel_g<<<dim3(22, 32, g), 256, 0, stream>>>(
                xb, wtg, wtu, combine, hbuf, gi * g);
            down_kernel_g<<<dim3(8, 32, 2), 256, 0, stream>>>(
                hbuf, wtd + (size_t)gi * g * HI, out, g);
        }
    } else {
        // fallback: round-3 validated path (~23.2 MB ws)
        float* combine = (float*)d_ws;
        __hip_bfloat16* hbuf = (__hip_bfloat16*)(combine + (size_t)TT * 8);
        router_kernel<<<TT, 64, 0, stream>>>(x, rw, rb, combine);
        dim3 blk(256);
        dim3 gH(ID / 128, TT / 128);
        dim3 gD(HD / 128, TT / 128);
        for (int p = 0; p < 8; ++p) {
            const float *wg, *wu, *wd;
            if (p < ER) {
                wg = rg + (size_t)p * HI;
                wu = ru + (size_t)p * HI;
                wd = rd + (size_t)p * HI;
            } else {
                wg = sg; wu = su; wd = sd;
            }
            gemm_kernel<0, 1><<<gH, blk, 0, stream>>>(x, wg, hbuf, nullptr, nullptr, TT, ID, HD, 0, 0);
            gemm_kernel<1, 1><<<gH, blk, 0, stream>>>(x, wu, hbuf, nullptr, nullptr, TT, ID, HD, 0, 0);
            gemm_kernel<2, 0><<<gD, blk, 0, stream>>>(hbuf, wd, nullptr, out, combine, TT, HD, ID, p, p == 0 ? 0 : 1);
        }
    }
}

// Round 4
// 1294.778 us; speedup vs baseline: 1.2754x; 1.0489x over previous
//
#include <hip/hip_runtime.h>
#include <hip/hip_bf16.h>

#define TT 4096   // B*S tokens
#define HD 1024   // hidden
#define ID 2816   // intermediate
#define ER 7      // routed experts
#define HI (HD * ID)

typedef short s16x8 __attribute__((ext_vector_type(8)));
typedef float f32x4 __attribute__((ext_vector_type(4)));

__device__ __forceinline__ uint32_t pkbf(float a, float b) {
    union { __hip_bfloat16 h[2]; uint32_t u; } z;
    z.h[0] = __float2bfloat16(a);
    z.h[1] = __float2bfloat16(b);
    return z.u;
}

__device__ __forceinline__ void gl_lds16(const void* g, void* l) {
    __builtin_amdgcn_global_load_lds(
        (const __attribute__((address_space(1))) uint32_t*)g,
        (__attribute__((address_space(3))) uint32_t*)l, 16, 0, 0);
}

// ---------------- router: 1 wave per token (fp32 in, fp32 out) ----------------
__global__ __launch_bounds__(64) void router_kernel(
    const float* __restrict__ x, const float* __restrict__ rw,
    const float* __restrict__ rbias, float* __restrict__ combine)
{
    const int t = blockIdx.x;
    const int lane = threadIdx.x;
    const float* xt = x + (size_t)t * HD;
    float acc[ER];
#pragma unroll
    for (int e = 0; e < ER; ++e) acc[e] = 0.f;
    for (int h = lane; h < HD; h += 64) {
        const float xv = xt[h];
#pragma unroll
        for (int e = 0; e < ER; ++e)
            acc[e] += xv * rw[h * ER + e];
    }
#pragma unroll
    for (int e = 0; e < ER; ++e) {
        float v = acc[e];
#pragma unroll
        for (int off = 32; off > 0; off >>= 1) v += __shfl_down(v, off, 64);
        acc[e] = v;
    }
    if (lane == 0) {
        float p[ER];
#pragma unroll
        for (int e = 0; e < ER; ++e) {
            const float lg = acc[e] + rbias[e];
            p[e] = 1.f / (1.f + __expf(-lg));
        }
        int i1 = 0;
#pragma unroll
        for (int e = 1; e < ER; ++e) if (p[e] > p[i1]) i1 = e;
        int i2 = (i1 == 0) ? 1 : 0;
#pragma unroll
        for (int e = 0; e < ER; ++e) {
            if (e == i1 || e == i2) continue;
            if (p[e] > p[i2]) i2 = e;
        }
        const float s = p[i1] + p[i2];
        float w[8];
#pragma unroll
        for (int e = 0; e < 8; ++e) w[e] = 0.f;
        w[i1] = p[i1] / s;
        w[i2] = p[i2] / s;
        w[7] = 1.f;   // shared-expert weight
        float* cb = combine + (size_t)t * 8;
#pragma unroll
        for (int e = 0; e < 8; ++e) cb[e] = w[e];
    }
}

// ---------------- transpose+convert: fp32 [K][N] -> bf16 [N][K], 8 matrices ----
__global__ __launch_bounds__(256) void txp_kernel(
    const float* __restrict__ Wsh, const float* __restrict__ Wrt,
    __hip_bfloat16* __restrict__ dst, int K, int N)
{
    __shared__ float lds[64 * 65];
    const int z = blockIdx.z;
    const float* src = (z < ER) ? (Wrt + (size_t)z * HI) : Wsh;
    __hip_bfloat16* out = dst + (size_t)z * HI;
    const int n0 = blockIdx.x * 64, k0 = blockIdx.y * 64;
    const int t = threadIdx.x;
    const int r = t >> 4, c = (t & 15) * 4;
#pragma unroll
    for (int i = 0; i < 4; ++i) {
        const float4 v = *(const float4*)(src + (size_t)(k0 + r + 16 * i) * N + n0 + c);
        float* p = &lds[(r + 16 * i) * 65 + c];
        p[0] = v.x; p[1] = v.y; p[2] = v.z; p[3] = v.w;
    }
    __syncthreads();
    const int nr = t >> 3, kc = (t & 7) * 8;
#pragma unroll
    for (int i = 0; i < 2; ++i) {
        const int nn = nr + 32 * i;
        uint32_t w[4];
#pragma unroll
        for (int j = 0; j < 4; ++j)
            w[j] = pkbf(lds[(kc + 2 * j) * 65 + nn], lds[(kc + 2 * j + 1) * 65 + nn]);
        *(uint4*)(out + (size_t)(n0 + nn) * K + k0 + kc) = *(uint4*)w;
    }
}

// ---------------- fp32 -> bf16 straight convert (x) ----------------
__global__ __launch_bounds__(256) void cvt_kernel(
    const float* __restrict__ a, __hip_bfloat16* __restrict__ o)
{
    const size_t i = ((size_t)blockIdx.x * 256 + threadIdx.x) * 8;
    const float4 v0 = *(const float4*)(a + i);
    const float4 v1 = *(const float4*)(a + i + 4);
    uint32_t w[4] = { pkbf(v0.x, v0.y), pkbf(v0.z, v0.w),
                      pkbf(v1.x, v1.y), pkbf(v1.z, v1.w) };
    *(uint4*)(o + i) = *(uint4*)w;
}

__global__ __launch_bounds__(256) void zero_kernel(float* __restrict__ o)
{
    const size_t i = ((size_t)blockIdx.x * 256 + threadIdx.x) * 4;
    *(float4*)(o + i) = float4{0.f, 0.f, 0.f, 0.f};
}

// ---------------- gu helpers (stage / mma) ----------------
__device__ __forceinline__ void gu_stage(
    const __hip_bfloat16* __restrict__ X,
    const __hip_bfloat16* __restrict__ Bg,
    const __hip_bfloat16* __restrict__ Bu,
    size_t aoff, size_t boff, int kb, char* lA, char* lG, char* lU)
{
    gl_lds16(X + aoff + kb, lA);
    gl_lds16(X + aoff + (size_t)64 * HD + kb, lA + 4096);
    gl_lds16(Bg + boff + kb, lG);
    gl_lds16(Bg + boff + (size_t)64 * HD + kb, lG + 4096);
    gl_lds16(Bu + boff + kb, lU);
    gl_lds16(Bu + boff + (size_t)64 * HD + kb, lU + 4096);
}

__device__ __forceinline__ void gu_mma(
    const __hip_bfloat16* __restrict__ sA,
    const __hip_bfloat16* __restrict__ sG,
    const __hip_bfloat16* __restrict__ sU,
    int wm, int wn, int r, int xh,
    f32x4 (&ag)[4][4], f32x4 (&au)[4][4])
{
    s16x8 af[4], bg[4], bu[4];
#pragma unroll
    for (int mi = 0; mi < 4; ++mi)
        af[mi] = *(const s16x8*)((const char*)sA + (wm + mi * 16 + r) * 64 + xh);
#pragma unroll
    for (int ni = 0; ni < 4; ++ni) {
        bg[ni] = *(const s16x8*)((const char*)sG + (wn + ni * 16 + r) * 64 + xh);
        bu[ni] = *(const s16x8*)((const char*)sU + (wn + ni * 16 + r) * 64 + xh);
    }
#pragma unroll
    for (int mi = 0; mi < 4; ++mi)
#pragma unroll
        for (int ni = 0; ni < 4; ++ni) {
            ag[mi][ni] = __builtin_amdgcn_mfma_f32_16x16x32_bf16(af[mi], bg[ni], ag[mi][ni], 0, 0, 0);
            au[mi][ni] = __builtin_amdgcn_mfma_f32_16x16x32_bf16(af[mi], bu[ni], au[mi][ni], 0, 0, 0);
        }
}

// ======================================================================
// gate+up GEMM, expert-group of g = gridDim.z experts in ONE launch.
// 2-phase double-buffer (T3 minimum recipe): stage next K-tile into buf^1
// BEFORE computing buf -> barrier drain waits on loads that had the whole
// MFMA phase in flight. K-loop unrolled by 2 so buffer index is static.
// + XOR swizzle (conflicts==0, r2/r3), XCD-exclusive chunking, combine fold.
// ======================================================================
__global__ __launch_bounds__(256) void gu_kernel_g(
    const __hip_bfloat16* __restrict__ X,
    const __hip_bfloat16* __restrict__ Wg,   // [8][ID][HD]
    const __hip_bfloat16* __restrict__ Wu,
    const float* __restrict__ combine,       // [TT][8]
    __hip_bfloat16* __restrict__ H,          // [TT][g*ID]
    int e0)
{
    __shared__ __hip_bfloat16 sA[2][128 * 32];
    __shared__ __hip_bfloat16 sG[2][128 * 32];
    __shared__ __hip_bfloat16 sU[2][128 * 32];
    const int tid = threadIdx.x;
    const int g = gridDim.z;

    // XCD-exclusive partition. nwg = 704*g; lid&7 == hardware XCD (heuristic).
    const int lid = blockIdx.x + 22 * blockIdx.y + 704 * blockIdx.z;
    const int xcd = lid & 7;
    const int w = lid >> 3;            // [0, 88g)
    const int xpe = 8 / g;             // XCDs per expert
    const int el = xcd / xpe;          // group-local expert
    const int t = xcd % xpe;
    const int cx = (xpe >= 2) ? 2 : 1;
    const int tw = 22 / cx;            // 11 or 22
    const int th = 32 / (xpe / cx);    // 8/16/32
    const int bx = (t % cx) * tw + (w % tw);
    const int by = (t / cx) * th + (w / tw);

    const int e = e0 + el;
    const int n0 = bx * 128, m0 = by * 128;
    const __hip_bfloat16* Bg = Wg + (size_t)e * HI;
    const __hip_bfloat16* Bu = Wu + (size_t)e * HI;
    const int ldH = g * ID;

    const int lane = tid & 63, wave = tid >> 6;
    const int wm = (wave >> 1) * 64, wn = (wave & 1) * 64;
    const int r = lane & 15, quad = lane >> 4;

    f32x4 ag[4][4], au[4][4];
#pragma unroll
    for (int i = 0; i < 4; ++i)
#pragma unroll
        for (int j = 0; j < 4; ++j) {
            ag[i][j] = (f32x4){0.f, 0.f, 0.f, 0.f};
            au[i][j] = (f32x4){0.f, 0.f, 0.f, 0.f};
        }

    // staging: row = tid>>2, 16B granule = tid&3, swizzled source slot.
    const int srow = tid >> 2;
    const int sk = ((tid & 3) ^ ((srow >> 1) & 3)) * 8;
    const size_t aoff = (size_t)(m0 + srow) * HD + sk;
    const size_t boff = (size_t)(n0 + srow) * HD + sk;
    char* lA0 = (char*)&sA[0][0] + tid * 16;
    char* lG0 = (char*)&sG[0][0] + tid * 16;
    char* lU0 = (char*)&sU[0][0] + tid * 16;
    char* lA1 = (char*)&sA[1][0] + tid * 16;
    char* lG1 = (char*)&sG[1][0] + tid * 16;
    char* lU1 = (char*)&sU[1][0] + tid * 16;

    // read-side XOR: granule quad lives at quad ^ ((r>>1)&3)
    const int xh = ((quad ^ ((r >> 1) & 3)) << 4);

    // dbuf prologue
    gu_stage(X, Bg, Bu, aoff, boff, 0, lA0, lG0, lU0);
    __syncthreads();

    for (int kb = 0; kb < HD; kb += 64) {
        if (kb + 32 < HD)
            gu_stage(X, Bg, Bu, aoff, boff, kb + 32, lA1, lG1, lU1);
        gu_mma(&sA[0][0], &sG[0][0], &sU[0][0], wm, wn, r, xh, ag, au);
        __syncthreads();
        if (kb + 64 < HD)
            gu_stage(X, Bg, Bu, aoff, boff, kb + 64, lA0, lG0, lU0);
        gu_mma(&sA[1][0], &sG[1][0], &sU[1][0], wm, wn, r, xh, ag, au);
        __syncthreads();
    }

    const int colb = el * ID;
#pragma unroll
    for (int mi = 0; mi < 4; ++mi)
#pragma unroll
        for (int i = 0; i < 4; ++i) {
            const int grow = m0 + wm + mi * 16 + quad * 4 + i;
            const float wcb = combine[(size_t)grow * 8 + e];
#pragma unroll
            for (int ni = 0; ni < 4; ++ni) {
                const int gcol = n0 + wn + ni * 16 + r;
                const float gv = ag[mi][ni][i];
                const float uv = au[mi][ni][i];
                const float hv = (gv / (1.f + __expf(-gv))) * uv * wcb;
                H[(size_t)grow * ldH + colb + gcol] = __float2bfloat16(hv);
            }
        }
}

// ---------------- down helpers ----------------
__device__ __forceinline__ void dn_stage(
    const __hip_bfloat16* __restrict__ Hb,
    const __hip_bfloat16* __restrict__ Wd,
    size_t abase, size_t bbase, int ldH, int kb, char* lA, char* lB)
{
    gl_lds16(Hb + abase + kb, lA);
    gl_lds16(Hb + abase + (size_t)64 * ldH + kb, lA + 4096);
    gl_lds16(Wd + bbase + kb, lB);
    gl_lds16(Wd + bbase + (size_t)64 * ID + kb, lB + 4096);
}

__device__ __forceinline__ void dn_mma(
    const __hip_bfloat16* __restrict__ sA,
    const __hip_bfloat16* __restrict__ sB,
    int wm, int wn, int r, int xh, f32x4 (&acc)[4][4])
{
    s16x8 af[4], bf[4];
#pragma unroll
    for (int mi = 0; mi < 4; ++mi)
        af[mi] = *(const s16x8*)((const char*)sA + (wm + mi * 16 + r) * 64 + xh);
#pragma unroll
    for (int ni = 0; ni < 4; ++ni)
        bf[ni] = *(const s16x8*)((const char*)sB + (wn + ni * 16 + r) * 64 + xh);
#pragma unroll
    for (int mi = 0; mi < 4; ++mi)
#pragma unroll
        for (int ni = 0; ni < 4; ++ni)
            acc[mi][ni] = __builtin_amdgcn_mfma_f32_16x16x32_bf16(af[mi], bf[ni], acc[mi][ni], 0, 0, 0);
}

// ======================================================================
// down GEMM over the g-expert group (combine folded into H), 2-phase dbuf.
// grid (8,32,2); z-split: g==1 -> ID halves; g>=2 -> expert halves.
// ======================================================================
__global__ __launch_bounds__(256) void down_kernel_g(
    const __hip_bfloat16* __restrict__ Hb,   // [TT][g*ID]
    const __hip_bfloat16* __restrict__ Wd,   // group base: [g][HD][ID]
    float* __restrict__ Out, int g)
{
    __shared__ __hip_bfloat16 sA[2][128 * 32];
    __shared__ __hip_bfloat16 sB[2][128 * 32];
    const int tid = threadIdx.x;

    const int lid = blockIdx.x + 8 * blockIdx.y + 256 * blockIdx.z;
    const int xcd = lid & 7;
    const int w = lid >> 3;                  // [0,64)
    const int sz = xcd >> 2;                 // split half
    const int q = xcd & 3;
    const int bx = (q & 1) * 4 + (w & 3);
    const int by = (q >> 1) * 16 + (w >> 2);

    const int n0 = bx * 128, m0 = by * 128;
    const int ldH = g * ID;
    int e_b, e_e, k0, k1;
    if (g == 1) { e_b = 0; e_e = 1; k0 = sz * (ID / 2); k1 = k0 + ID / 2; }
    else        { e_b = sz * (g >> 1); e_e = e_b + (g >> 1); k0 = 0; k1 = ID; }

    const int lane = tid & 63, wave = tid >> 6;
    const int wm = (wave >> 1) * 64, wn = (wave & 1) * 64;
    const int r = lane & 15, quad = lane >> 4;

    f32x4 acc[4][4];
#pragma unroll
    for (int i = 0; i < 4; ++i)
#pragma unroll
        for (int j = 0; j < 4; ++j)
            acc[i][j] = (f32x4){0.f, 0.f, 0.f, 0.f};

    const int srow = tid >> 2;
    const int sk = ((tid & 3) ^ ((srow >> 1) & 3)) * 8;
    char* lA0 = (char*)&sA[0][0] + tid * 16;
    char* lB0 = (char*)&sB[0][0] + tid * 16;
    char* lA1 = (char*)&sA[1][0] + tid * 16;
    char* lB1 = (char*)&sB[1][0] + tid * 16;
    const int xh = ((quad ^ ((r >> 1) & 3)) << 4);

    for (int e = e_b; e < e_e; ++e) {
        const size_t abase = (size_t)(m0 + srow) * ldH + (size_t)e * ID + sk;
        const size_t bbase = (size_t)e * HI + (size_t)(n0 + srow) * ID + sk;

        dn_stage(Hb, Wd, abase, bbase, ldH, k0, lA0, lB0);
        __syncthreads();
        for (int kb = k0; kb < k1; kb += 64) {
            if (kb + 32 < k1)
                dn_stage(Hb, Wd, abase, bbase, ldH, kb + 32, lA1, lB1);
            dn_mma(&sA[0][0], &sB[0][0], wm, wn, r, xh, acc);
            __syncthreads();
            if (kb + 64 < k1)
                dn_stage(Hb, Wd, abase, bbase, ldH, kb + 64, lA0, lB0);
            dn_mma(&sA[1][0], &sB[1][0], wm, wn, r, xh, acc);
            __syncthreads();
        }
    }

#pragma unroll
    for (int mi = 0; mi < 4; ++mi)
#pragma unroll
        for (int i = 0; i < 4; ++i) {
            const int grow = m0 + wm + mi * 16 + quad * 4 + i;
#pragma unroll
            for (int ni = 0; ni < 4; ++ni) {
                const int gcol = n0 + wn + ni * 16 + r;
                atomicAdd(&Out[(size_t)grow * HD + gcol], acc[mi][ni][i]);
            }
        }
}

// ================= fallback path (round-3, validated) =================
template <int MODE, int AF32>
__global__ __launch_bounds__(256) void gemm_kernel(
    const void* __restrict__ Av, const float* __restrict__ B,
    __hip_bfloat16* __restrict__ Hbuf, float* __restrict__ Out,
    const float* __restrict__ combine, int M, int N, int K, int wcol, int beta)
{
    __shared__ uint32_t ldsA[128 * 20];
    __shared__ uint32_t ldsB[128 * 20];
    const int tid = threadIdx.x;
    const int n0 = blockIdx.x * 128;
    const int m0 = blockIdx.y * 128;
    const int lane = tid & 63, wave = tid >> 6;
    const int wm = (wave >> 1) * 64, wn = (wave & 1) * 64;
    const int r = lane & 15, quad = lane >> 4;
    f32x4 acc[4][4];
#pragma unroll
    for (int i = 0; i < 4; ++i)
#pragma unroll
        for (int j = 0; j < 4; ++j) acc[i][j] = (f32x4){0.f, 0.f, 0.f, 0.f};
    for (int kb = 0; kb < K; kb += 32) {
        if (AF32) {
            const float* A = (const float*)Av;
            const int arow = tid >> 1, ah = tid & 1;
            const float* ap = A + (size_t)(m0 + arow) * K + kb + ah * 16;
            const float4 f0 = *(const float4*)ap;
            const float4 f1 = *(const float4*)(ap + 4);
            const float4 f2 = *(const float4*)(ap + 8);
            const float4 f3 = *(const float4*)(ap + 12);
            uint4 w0, w1;
            w0.x = pkbf(f0.x, f0.y); w0.y = pkbf(f0.z, f0.w);
            w0.z = pkbf(f1.x, f1.y); w0.w = pkbf(f1.z, f1.w);
            w1.x = pkbf(f2.x, f2.y); w1.y = pkbf(f2.z, f2.w);
            w1.z = pkbf(f3.x, f3.y); w1.w = pkbf(f3.z, f3.w);
            *(uint4*)&ldsA[arow * 20 + ah * 8] = w0;
            *(uint4*)&ldsA[arow * 20 + ah * 8 + 4] = w1;
        } else {
            const __hip_bfloat16* A = (const __hip_bfloat16*)Av;
            const int arow = tid >> 2, akc = tid & 3;
            const uint4 v0 = *(const uint4*)(A + (size_t)(m0 + arow) * K + kb + akc * 8);
            const uint4 v1 = *(const uint4*)(A + (size_t)(m0 + arow + 64) * K + kb + akc * 8);
            *(uint4*)&ldsA[arow * 20 + akc * 4] = v0;
            *(uint4*)&ldsA[(arow + 64) * 20 + akc * 4] = v1;
        }
        {
            const int bkp = tid >> 4, bnc = tid & 15;
            const float* bp0 = B + (size_t)(kb + 2 * bkp) * N + n0 + bnc * 8;
            const float* bp1 = bp0 + N;
            const float4 a0 = *(const float4*)bp0;
            const float4 a1 = *(const float4*)(bp0 + 4);
            const float4 b0 = *(const float4*)bp1;
            const float4 b1 = *(const float4*)(bp1 + 4);
            const float r0[8] = {a0.x, a0.y, a0.z, a0.w, a1.x, a1.y, a1.z, a1.w};
            const float r1[8] = {b0.x, b0.y, b0.z, b0.w, b1.x, b1.y, b1.z, b1.w};
            const int grp = (((bkp >> 2) ^ (bnc & 3)) << 2);
            const int kk = bkp & 3;
#pragma unroll
            for (int j = 0; j < 8; ++j)
                ldsB[(bnc * 8 + j) * 20 + grp + kk] = pkbf(r0[j], r1[j]);
        }
        __syncthreads();
        s16x8 af[4], bfr[4];
#pragma unroll
        for (int mi = 0; mi < 4; ++mi)
            af[mi] = *(const s16x8*)&ldsA[(wm + mi * 16 + r) * 20 + quad * 4];
#pragma unroll
        for (int ni = 0; ni < 4; ++ni) {
            const int nl = wn + ni * 16 + r;
            bfr[ni] = *(const s16x8*)&ldsB[nl * 20 + ((quad ^ ((nl >> 3) & 3)) << 2)];
        }
#pragma unroll
        for (int mi = 0; mi < 4; ++mi)
#pragma unroll
            for (int ni = 0; ni < 4; ++ni)
                acc[mi][ni] = __builtin_amdgcn_mfma_f32_16x16x32_bf16(af[mi], bfr[ni], acc[mi][ni], 0, 0, 0);
        __syncthreads();
    }
#pragma unroll
    for (int mi = 0; mi < 4; ++mi)
#pragma unroll
        for (int i = 0; i < 4; ++i) {
            const int grow = m0 + wm + mi * 16 + quad * 4 + i;
#pragma unroll
            for (int ni = 0; ni < 4; ++ni) {
                const int gcol = n0 + wn + ni * 16 + r;
                const float v = acc[mi][ni][i];
                if (MODE == 0) {
                    Hbuf[(size_t)grow * N + gcol] = __float2bfloat16(v / (1.f + __expf(-v)));
                } else if (MODE == 1) {
                    const size_t idx = (size_t)grow * N + gcol;
                    Hbuf[idx] = __float2bfloat16(__bfloat162float(Hbuf[idx]) * v);
                } else {
                    const size_t idx = (size_t)grow * N + gcol;
                    const float w = combine[(size_t)grow * 8 + wcol];
                    Out[idx] = (beta ? Out[idx] : 0.f) + w * v;
                }
            }
        }
}

extern "C" void kernel_launch(void* const* d_in, const int* in_sizes, int n_in,
                              void* d_out, int out_size, void* d_ws, size_t ws_size,
                              hipStream_t stream)
{
    (void)in_sizes; (void)n_in; (void)out_size;
    const float* x  = (const float*)d_in[0];
    const float* rw = (const float*)d_in[1];
    const float* rb = (const float*)d_in[2];
    const float* sg = (const float*)d_in[3];
    const float* su = (const float*)d_in[4];
    const float* sd = (const float*)d_in[5];
    const float* rg = (const float*)d_in[6];
    const float* ru = (const float*)d_in[7];
    const float* rd = (const float*)d_in[8];
    float* out = (float*)d_out;

    const size_t SZ_COMBINE = (size_t)TT * 8 * 4;
    const size_t SZ_XB      = (size_t)TT * HD * 2;
    const size_t SZ_W       = (size_t)8 * HI * 2;

    // largest expert-group g whose hbuf fits the workspace
    int g = 0;
    for (int c = 8; c >= 1; c >>= 1) {
        const size_t need = SZ_COMBINE + SZ_XB + (size_t)TT * c * ID * 2 + 3 * SZ_W;
        if (ws_size >= need) { g = c; break; }
    }

    if (g) {
        char* p = (char*)d_ws;
        float* combine = (float*)p;            p += SZ_COMBINE;
        __hip_bfloat16* xb   = (__hip_bfloat16*)p; p += SZ_XB;
        __hip_bfloat16* hbuf = (__hip_bfloat16*)p; p += (size_t)TT * g * ID * 2;
        __hip_bfloat16* wtg  = (__hip_bfloat16*)p; p += SZ_W;
        __hip_bfloat16* wtu  = (__hip_bfloat16*)p; p += SZ_W;
        __hip_bfloat16* wtd  = (__hip_bfloat16*)p;

        zero_kernel<<<(TT * HD) / 1024, 256, 0, stream>>>(out);
        cvt_kernel<<<(TT * HD) / 2048, 256, 0, stream>>>(x, xb);
        txp_kernel<<<dim3(ID / 64, HD / 64, 8), 256, 0, stream>>>(sg, rg, wtg, HD, ID);
        txp_kernel<<<dim3(ID / 64, HD / 64, 8), 256, 0, stream>>>(su, ru, wtu, HD, ID);
        txp_kernel<<<dim3(HD / 64, ID / 64, 8), 256, 0, stream>>>(sd, rd, wtd, ID, HD);
        router_kernel<<<TT, 64, 0, stream>>>(x, rw, rb, combine);

        for (int gi = 0; gi < 8 / g; ++gi) {
            gu_kernel_g<<<dim3(22, 32, g), 256, 0, stream>>>(
                xb, wtg, wtu, combine, hbuf, gi * g);
            down_kernel_g<<<dim3(8, 32, 2), 256, 0, stream>>>(
                hbuf, wtd + (size_t)gi * g * HI, out, g);
        }
    } else {
        // fallback: round-3 validated path (~23.2 MB ws)
        float* combine = (float*)d_ws;
        __hip_bfloat16* hbuf = (__hip_bfloat16*)(combine + (size_t)TT * 8);
        router_kernel<<<TT, 64, 0, stream>>>(x, rw, rb, combine);
        dim3 blk(256);
        dim3 gH(ID / 128, TT / 128);
        dim3 gD(HD / 128, TT / 128);
        for (int p = 0; p < 8; ++p) {
            const float *wg, *wu, *wd;
            if (p < ER) {
                wg = rg + (size_t)p * HI;
                wu = ru + (size_t)p * HI;
                wd = rd + (size_t)p * HI;
            } else {
                wg = sg; wu = su; wd = sd;
            }
            gemm_kernel<0, 1><<<gH, blk, 0, stream>>>(x, wg, hbuf, nullptr, nullptr, TT, ID, HD, 0, 0);
            gemm_kernel<1, 1><<<gH, blk, 0, stream>>>(x, wu, hbuf, nullptr, nullptr, TT, ID, HD, 0, 0);
            gemm_kernel<2, 0><<<gD, blk, 0, stream>>>(hbuf, wd, nullptr, out, combine, TT, HD, ID, p, p == 0 ? 0 : 1);
        }
    }
}